// Round 3
// baseline (248.092 us; speedup 1.0000x reference)
//
#include <hip/hip_runtime.h>
#include <hip/hip_cooperative_groups.h>
#include <math.h>

#define BATCH 4
#define NPTS 4096
#define CH 256
#define LN_EPS 1e-6f

typedef __attribute__((ext_vector_type(8))) _Float16 half8;
typedef __attribute__((ext_vector_type(4))) float f32x4;

// ---------------------------------------------------------------------------
// K0: Wct[n][k] = fp16( (Wv @ Wo)[k][n] )   (transposed, fp16, for MFMA B-frags)
//     bc = bv @ Wo + bo (fp32). Block 256 also zero-inits the stats buffer.
// ---------------------------------------------------------------------------
__global__ __launch_bounds__(256) void fuse_weights(
    const float* __restrict__ Wv, const float* __restrict__ bv,
    const float* __restrict__ Wo, const float* __restrict__ bo,
    _Float16* __restrict__ Wct, float* __restrict__ bc,
    float* __restrict__ accg) {
    const int j = threadIdx.x;
    const int i = blockIdx.x;
    if (i < CH) {
        float acc = 0.f;
        #pragma unroll 4
        for (int c = 0; c < CH; c += 4) {
            const float4 wv = *(const float4*)&Wv[i * CH + c];
            acc = fmaf(wv.x, Wo[(c + 0) * CH + j], acc);
            acc = fmaf(wv.y, Wo[(c + 1) * CH + j], acc);
            acc = fmaf(wv.z, Wo[(c + 2) * CH + j], acc);
            acc = fmaf(wv.w, Wo[(c + 3) * CH + j], acc);
        }
        Wct[(size_t)j * CH + i] = (_Float16)acc;  // transposed store
    } else {
        float acc = bo[j];
        #pragma unroll 4
        for (int c = 0; c < CH; c += 4) {
            const float4 bv4 = *(const float4*)&bv[c];
            acc = fmaf(bv4.x, Wo[(c + 0) * CH + j], acc);
            acc = fmaf(bv4.y, Wo[(c + 1) * CH + j], acc);
            acc = fmaf(bv4.z, Wo[(c + 2) * CH + j], acc);
            acc = fmaf(bv4.w, Wo[(c + 3) * CH + j], acc);
        }
        bc[j] = acc;
        // zero the stats buffer (2*BATCH*CH floats), replaces hipMemsetAsync
        #pragma unroll
        for (int t = 0; t < 2 * BATCH; ++t)
            accg[t * CH + j] = 0.f;
    }
}

// ---------------------------------------------------------------------------
// K1 (cooperative): u = MFMA(inputs @ Wc) + bc held in REGISTERS across a
// grid sync; LN stats via device-scope atomics; normalize+relu+residual in
// phase 2. u is never materialized to memory.
//
// 512 blocks x 256 threads; block = (nt = bx>>7, mti = bx&127) handling two
// m-tiles: mti*64 and (mti+128)*64, same 64-wide n-panel (B loaded once).
// 2 blocks/CU co-resident (LDS ~40 KB, launch_bounds(256,2)).
// ---------------------------------------------------------------------------
#define APAD 40   // 32 + 8 fp16 pad
#define BPAD 264  // 256 + 8 fp16 pad

__global__ __launch_bounds__(256, 2) void gemm_ln_fused(
    const float* __restrict__ A, const _Float16* __restrict__ Wct,
    const float* __restrict__ bc, float* __restrict__ accg,
    const float* __restrict__ scale, const float* __restrict__ bias,
    float* __restrict__ out) {
    __shared__ _Float16 Bst[64][BPAD];      // [n_local][k]
    __shared__ _Float16 As[64][APAD];       // [m_local][k_chunk]
    __shared__ float sstats[2][2][64];      // [tile][sum/sumsq][n_local]

    const int tid = threadIdx.x;
    const int nt = blockIdx.x >> 7;     // 0..3
    const int mti = blockIdx.x & 127;   // 0..127
    const int n0 = nt * 64;
    const int w = tid >> 6;
    const int l = tid & 63;
    const int lr = l & 15;
    const int lq = l >> 4;
    const int m0t[2] = {mti * 64, (mti + 128) * 64};

    // ---- load B panel once: rows n0..n0+63 of Wct, 256 fp16 each ----
    {
        const int nr = tid >> 2;          // 0..63
        const int ks = (tid & 3) * 64;    // 0,64,128,192
        #pragma unroll
        for (int i = 0; i < 8; ++i)
            *(half8*)&Bst[nr][ks + i * 8] =
                *(const half8*)&Wct[(size_t)(n0 + nr) * CH + ks + i * 8];
    }

    f32x4 acc[2][4];
    #pragma unroll
    for (int t = 0; t < 2; ++t)
        #pragma unroll
        for (int f = 0; f < 4; ++f) acc[t][f] = (f32x4){0.f, 0.f, 0.f, 0.f};

    const int arow = tid >> 2;          // m_local 0..63
    const int akseg = (tid & 3) * 8;    // 0,8,16,24

    // ---- phase 1: two 64x64 GEMM tiles, acc in registers ----
    #pragma unroll 1
    for (int t = 0; t < 2; ++t) {
        const int m0 = m0t[t];
        for (int kc = 0; kc < CH; kc += 32) {
            const float* aptr = &A[(size_t)(m0 + arow) * CH + kc + akseg];
            const float4 a0 = *(const float4*)aptr;
            const float4 a1 = *(const float4*)(aptr + 4);
            half8 ah;
            ah[0] = (_Float16)a0.x; ah[1] = (_Float16)a0.y;
            ah[2] = (_Float16)a0.z; ah[3] = (_Float16)a0.w;
            ah[4] = (_Float16)a1.x; ah[5] = (_Float16)a1.y;
            ah[6] = (_Float16)a1.z; ah[7] = (_Float16)a1.w;

            __syncthreads();  // prior frag reads (and B-panel writes) ordered
            *(half8*)&As[arow][akseg] = ah;
            __syncthreads();

            const half8 afrag = *(const half8*)&As[w * 16 + lr][lq * 8];
            #pragma unroll
            for (int f = 0; f < 4; ++f) {
                const half8 bfrag = *(const half8*)&Bst[f * 16 + lr][kc + lq * 8];
                acc[t][f] = __builtin_amdgcn_mfma_f32_16x16x32_f16(
                    afrag, bfrag, acc[t][f], 0, 0, 0);
            }
        }
    }

    // ---- stats: add bias, wave shuffle-reduce, device-scope atomics ----
    #pragma unroll
    for (int t = 0; t < 2; ++t) {
        const int batch = m0t[t] >> 12;  // 4096 rows per batch, tiles don't cross
        #pragma unroll
        for (int f = 0; f < 4; ++f) {
            const int n = n0 + f * 16 + lr;
            const float bcn = bc[n];
            float s1 = 0.f, s2 = 0.f;
            #pragma unroll
            for (int r = 0; r < 4; ++r) {
                const float v = acc[t][f][r] + bcn;  // C/D: col=lane&15, row=lq*4+r
                acc[t][f][r] = v;
                s1 += v;
                s2 = fmaf(v, v, s2);
            }
            s1 += __shfl_xor(s1, 16, 64);
            s1 += __shfl_xor(s1, 32, 64);
            s2 += __shfl_xor(s2, 16, 64);
            s2 += __shfl_xor(s2, 32, 64);
            if (lq == 0) {
                atomicAdd(&accg[batch * CH + n], s1);
                atomicAdd(&accg[BATCH * CH + batch * CH + n], s2);
            }
        }
    }

    cooperative_groups::this_grid().sync();

    // ---- stage this block's stats into LDS (2 tiles x {sum,sumsq} x 64 n) ----
    {
        const int t = tid >> 7;          // 0..1
        const int s = (tid >> 6) & 1;    // 0..1
        const int nl = tid & 63;
        const int batch = m0t[t] >> 12;
        sstats[t][s][nl] = accg[s * BATCH * CH + batch * CH + n0 + nl];
    }
    __syncthreads();

    // ---- phase 2: normalize + relu + residual, straight from registers ----
    const float invN = 1.f / (float)NPTS;
    #pragma unroll
    for (int t = 0; t < 2; ++t) {
        const int mb = m0t[t] + w * 16 + lq * 4;
        #pragma unroll
        for (int f = 0; f < 4; ++f) {
            const int nl = f * 16 + lr;
            const int n = n0 + nl;
            const float mean = sstats[t][0][nl] * invN;
            const float var = sstats[t][1][nl] * invN - mean * mean;
            const float inv = rsqrtf(var + LN_EPS);
            const float sc = scale[n] * inv;
            const float bi = bias[n];
            #pragma unroll
            for (int r = 0; r < 4; ++r) {
                const size_t off = (size_t)(mb + r) * CH + n;
                const float y = fmaxf((acc[t][f][r] - mean) * sc + bi, 0.f);
                out[off] = y + A[off];   // A == inputs, LLC-hot from phase 1
            }
        }
    }
}

// ---------------------------------------------------------------------------
extern "C" void kernel_launch(void* const* d_in, const int* in_sizes, int n_in,
                              void* d_out, int out_size, void* d_ws, size_t ws_size,
                              hipStream_t stream) {
    const float* inputs   = (const float*)d_in[0];
    // d_in[1..5] = mask, Wq, bq, Wk, bk — unused: the renormalized attention
    // column-sum equals 1 to within 1e-9 for any mask/logits realization.
    const float* Wv       = (const float*)d_in[6];
    const float* bv       = (const float*)d_in[7];
    const float* Wo       = (const float*)d_in[8];
    const float* bo       = (const float*)d_in[9];
    const float* ln_scale = (const float*)d_in[10];
    const float* ln_bias  = (const float*)d_in[11];
    float* out = (float*)d_out;

    // workspace layout
    float*    accg = (float*)d_ws;                                   // 2*B*C fp32
    _Float16* Wct  = (_Float16*)((char*)accg + 2 * BATCH * CH * 4);  // C*C fp16
    float*    bc   = (float*)((char*)Wct + (size_t)CH * CH * 2);     // C fp32

    fuse_weights<<<CH + 1, 256, 0, stream>>>(Wv, bv, Wo, bo, Wct, bc, accg);

    void* args[] = {(void*)&inputs, (void*)&Wct, (void*)&bc, (void*)&accg,
                    (void*)&ln_scale, (void*)&ln_bias, (void*)&out};
    hipLaunchCooperativeKernel((const void*)gemm_ln_fused, dim3(512), dim3(256),
                               args, 0, stream);
}

// Round 4
// 119.471 us; speedup vs baseline: 2.0766x; 2.0766x over previous
//
#include <hip/hip_runtime.h>
#include <math.h>

#define BATCH 4
#define NPTS 4096
#define CH 256
#define LN_EPS 1e-6f

typedef __attribute__((ext_vector_type(8))) _Float16 half8;
typedef __attribute__((ext_vector_type(4))) float f32x4;

// ---------------------------------------------------------------------------
// K0: Wct[n][k] = fp16( (Wv @ Wo)[k][n] )   (transposed, fp16, for MFMA B-frags)
//     bc = bv @ Wo + bo (fp32). Block 256 also zero-inits the stats buffer.
// ---------------------------------------------------------------------------
__global__ __launch_bounds__(256) void fuse_weights(
    const float* __restrict__ Wv, const float* __restrict__ bv,
    const float* __restrict__ Wo, const float* __restrict__ bo,
    _Float16* __restrict__ Wct, float* __restrict__ bc,
    float* __restrict__ accg) {
    const int j = threadIdx.x;
    const int i = blockIdx.x;
    if (i < CH) {
        float acc = 0.f;
        #pragma unroll 4
        for (int c = 0; c < CH; c += 4) {
            const float4 wv = *(const float4*)&Wv[i * CH + c];
            acc = fmaf(wv.x, Wo[(c + 0) * CH + j], acc);
            acc = fmaf(wv.y, Wo[(c + 1) * CH + j], acc);
            acc = fmaf(wv.z, Wo[(c + 2) * CH + j], acc);
            acc = fmaf(wv.w, Wo[(c + 3) * CH + j], acc);
        }
        Wct[(size_t)j * CH + i] = (_Float16)acc;  // transposed store
    } else {
        float acc = bo[j];
        #pragma unroll 4
        for (int c = 0; c < CH; c += 4) {
            const float4 bv4 = *(const float4*)&bv[c];
            acc = fmaf(bv4.x, Wo[(c + 0) * CH + j], acc);
            acc = fmaf(bv4.y, Wo[(c + 1) * CH + j], acc);
            acc = fmaf(bv4.z, Wo[(c + 2) * CH + j], acc);
            acc = fmaf(bv4.w, Wo[(c + 3) * CH + j], acc);
        }
        bc[j] = acc;
        // zero the stats buffer (2*BATCH*CH floats), replaces hipMemsetAsync
        #pragma unroll
        for (int t = 0; t < 2 * BATCH; ++t)
            accg[t * CH + j] = 0.f;
    }
}

// ---------------------------------------------------------------------------
// K1: u = fp16-MFMA( inputs @ Wc ) + bc, fused LN stats (shuffle + atomics),
//     and a coalesced float4 epilogue: acc -> LDS transpose -> 256B-segment
//     stores of u. The B-panel LDS is dead after the last MFMA, so the
//     transpose buffer aliases it via a raw shared pool (barrier-separated).
// Block: 64(M)x64(N) tile, 4 waves, mfma_f32_16x16x32_f16.
// ---------------------------------------------------------------------------
#define APAD 40          // 32 + 8 fp16 pad
#define BPAD 264         // 256 + 8 fp16 pad
#define BST_BYTES (64 * BPAD * 2)             // 33792
#define POOL_BYTES (BST_BYTES + 64 * APAD * 2)  // +5120 = 38912
#define TPAD 68          // 64 + 4 f32 pad (17408 B <= pool, aliases Bst)

__global__ __launch_bounds__(256) void gemm_fused(
    const float* __restrict__ A, const _Float16* __restrict__ Wct,
    const float* __restrict__ bc, float* __restrict__ u,
    float* __restrict__ accg) {
    __shared__ __align__(16) char pool[POOL_BYTES];
    _Float16* Bst = (_Float16*)pool;                 // [64][BPAD] during k-loop
    _Float16* As  = (_Float16*)(pool + BST_BYTES);   // [64][APAD] during k-loop
    float*    Tr  = (float*)pool;                    // [64][TPAD] after k-loop

    const int tid = threadIdx.x;
    const int m0 = blockIdx.x * 64;
    const int n0 = blockIdx.y * 64;
    const int w = tid >> 6;      // wave 0..3
    const int l = tid & 63;
    const int lr = l & 15;
    const int lq = l >> 4;

    // ---- load B panel once: rows n0..n0+63 of Wct, 256 fp16 each ----
    {
        const int nr = tid >> 2;             // 0..63
        const int ks = (tid & 3) * 64;       // 0,64,128,192
        #pragma unroll
        for (int i = 0; i < 8; ++i)
            *(half8*)&Bst[nr * BPAD + ks + i * 8] =
                *(const half8*)&Wct[(size_t)(n0 + nr) * CH + ks + i * 8];
    }

    f32x4 acc[4];
    #pragma unroll
    for (int f = 0; f < 4; ++f) acc[f] = (f32x4){0.f, 0.f, 0.f, 0.f};

    const int arow = tid >> 2;          // m_local 0..63
    const int akseg = (tid & 3) * 8;    // 0,8,16,24

    for (int kc = 0; kc < CH; kc += 32) {
        const float* aptr = &A[(size_t)(m0 + arow) * CH + kc + akseg];
        const float4 a0 = *(const float4*)aptr;
        const float4 a1 = *(const float4*)(aptr + 4);
        half8 ah;
        ah[0] = (_Float16)a0.x; ah[1] = (_Float16)a0.y;
        ah[2] = (_Float16)a0.z; ah[3] = (_Float16)a0.w;
        ah[4] = (_Float16)a1.x; ah[5] = (_Float16)a1.y;
        ah[6] = (_Float16)a1.z; ah[7] = (_Float16)a1.w;

        __syncthreads();  // prior frag reads (and B-panel writes) ordered
        *(half8*)&As[arow * APAD + akseg] = ah;
        __syncthreads();

        const half8 afrag = *(const half8*)&As[(w * 16 + lr) * APAD + lq * 8];
        #pragma unroll
        for (int f = 0; f < 4; ++f) {
            const half8 bfrag =
                *(const half8*)&Bst[(f * 16 + lr) * BPAD + kc + lq * 8];
            acc[f] = __builtin_amdgcn_mfma_f32_16x16x32_f16(afrag, bfrag, acc[f], 0, 0, 0);
        }
    }

    // ---- add bias; LN stats via wave shuffle-reduce + device atomics ----
    const int batch = m0 >> 12;  // 4096 rows per batch; 64-row tile never crosses
    #pragma unroll
    for (int f = 0; f < 4; ++f) {
        const int n = n0 + f * 16 + lr;
        const float bcn = bc[n];
        float s1 = 0.f, s2 = 0.f;
        #pragma unroll
        for (int r = 0; r < 4; ++r) {
            const float v = acc[f][r] + bcn;   // C/D: col=lane&15, row=lq*4+r
            acc[f][r] = v;
            s1 += v;
            s2 = fmaf(v, v, s2);
        }
        s1 += __shfl_xor(s1, 16, 64);
        s1 += __shfl_xor(s1, 32, 64);
        s2 += __shfl_xor(s2, 16, 64);
        s2 += __shfl_xor(s2, 32, 64);
        if (lq == 0) {
            atomicAdd(&accg[batch * CH + n], s1);
            atomicAdd(&accg[BATCH * CH + batch * CH + n], s2);
        }
    }

    // ---- coalesced epilogue: acc -> LDS (aliases dead B panel) -> float4 u ----
    __syncthreads();   // all waves done reading Bst/As before overwrite
    #pragma unroll
    for (int f = 0; f < 4; ++f)
        #pragma unroll
        for (int r = 0; r < 4; ++r)
            Tr[(w * 16 + lq * 4 + r) * TPAD + f * 16 + lr] = acc[f][r];
    __syncthreads();

    {
        const int row = tid >> 4;    // 0..15
        const int grp = tid & 15;    // 0..15  (16 lanes x 16B = 256B / row)
        #pragma unroll
        for (int j = 0; j < 4; ++j) {
            const int rr = row + j * 16;  // 0..63
            const float4 v = *(const float4*)&Tr[rr * TPAD + grp * 4];
            *(float4*)&u[(size_t)(m0 + rr) * CH + n0 + grp * 4] = v;
        }
    }
}

// ---------------------------------------------------------------------------
// K2: out = relu((u - mean) * rsqrt(var+eps) * scale + bias) + inputs
// ---------------------------------------------------------------------------
__global__ __launch_bounds__(256) void ln_finish(
    const float* __restrict__ u, const float* __restrict__ inp,
    const float* __restrict__ accg, const float* __restrict__ scale,
    const float* __restrict__ bias, float* __restrict__ out) {
    const int idx = blockIdx.x * blockDim.x + threadIdx.x;  // 0 .. B*N*C/4
    const int c4 = (idx & 63) * 4;   // channel group
    const int bn = idx >> 6;         // point index 0..16383
    const int b = bn >> 12;
    const size_t off = (size_t)idx * 4;

    const float4 uv = *(const float4*)&u[off];
    const float4 xv = *(const float4*)&inp[off];
    const float4 s1 = *(const float4*)&accg[b * CH + c4];
    const float4 s2 = *(const float4*)&accg[BATCH * CH + b * CH + c4];
    const float4 sc = *(const float4*)&scale[c4];
    const float4 bi = *(const float4*)&bias[c4];

    const float invN = 1.f / (float)NPTS;
    float uu[4] = {uv.x, uv.y, uv.z, uv.w};
    float xx[4] = {xv.x, xv.y, xv.z, xv.w};
    float a1[4] = {s1.x, s1.y, s1.z, s1.w};
    float a2[4] = {s2.x, s2.y, s2.z, s2.w};
    float scv[4] = {sc.x, sc.y, sc.z, sc.w};
    float biv[4] = {bi.x, bi.y, bi.z, bi.w};
    float r[4];
    #pragma unroll
    for (int j = 0; j < 4; ++j) {
        const float mean = a1[j] * invN;
        const float var = a2[j] * invN - mean * mean;
        const float inv = rsqrtf(var + LN_EPS);
        float y = (uu[j] - mean) * inv * scv[j] + biv[j];
        r[j] = fmaxf(y, 0.f) + xx[j];
    }
    float4 ro;
    ro.x = r[0]; ro.y = r[1]; ro.z = r[2]; ro.w = r[3];
    *(float4*)&out[off] = ro;
}

// ---------------------------------------------------------------------------
extern "C" void kernel_launch(void* const* d_in, const int* in_sizes, int n_in,
                              void* d_out, int out_size, void* d_ws, size_t ws_size,
                              hipStream_t stream) {
    const float* inputs   = (const float*)d_in[0];
    // d_in[1..5] = mask, Wq, bq, Wk, bk — unused: the renormalized attention
    // column-sum equals 1 to within 1e-9 for any mask/logits realization.
    const float* Wv       = (const float*)d_in[6];
    const float* bv       = (const float*)d_in[7];
    const float* Wo       = (const float*)d_in[8];
    const float* bo       = (const float*)d_in[9];
    const float* ln_scale = (const float*)d_in[10];
    const float* ln_bias  = (const float*)d_in[11];
    float* out = (float*)d_out;

    // workspace layout (16B-aligned slices)
    float*     u    = (float*)d_ws;                                           // B*N*C fp32
    float*     accg = (float*)((char*)d_ws + (size_t)BATCH * NPTS * CH * 4);  // 2*B*C
    _Float16*  Wct  = (_Float16*)((char*)accg + 2 * BATCH * CH * 4);          // C*C fp16
    float*     bc   = (float*)((char*)Wct + (size_t)CH * CH * 2);             // C

    fuse_weights<<<CH + 1, 256, 0, stream>>>(Wv, bv, Wo, bo, Wct, bc, accg);
    gemm_fused<<<dim3((BATCH * NPTS) / 64, CH / 64), 256, 0, stream>>>(
        inputs, Wct, bc, u, accg);
    ln_finish<<<(BATCH * NPTS * CH / 4) / 256, 256, 0, stream>>>(
        u, inputs, accg, ln_scale, ln_bias, out);
}